// Round 10
// baseline (638.693 us; speedup 1.0000x reference)
//
#include <hip/hip_runtime.h>

#define N_ENT  100000
#define MPAD   100096           // 782 * 128
#define EHALF  500000
#define NE2    1000000
#define D      256
#define NREL   200
#define BN_EPS 1e-5f

typedef __attribute__((ext_vector_type(8))) short  bf16x8;
typedef __attribute__((ext_vector_type(8))) ushort us8;
typedef __attribute__((ext_vector_type(4))) float  f32x4;

__device__ __forceinline__ ushort f2b(float f) {
    unsigned u = __float_as_uint(f);
    return (ushort)((u + 0x7fffu + ((u >> 16) & 1u)) >> 16);
}
__device__ __forceinline__ float b2f(ushort u) {
    return __uint_as_float((unsigned)u << 16);
}

// bf16-pair (one dword) elementwise product accumulate: a += (x .* r) * sc
__device__ __forceinline__ void bacc(unsigned xa, unsigned ra, float sc, float2& a) {
    float x0 = __uint_as_float(xa << 16);
    float x1 = __uint_as_float(xa & 0xFFFF0000u);
    float r0 = __uint_as_float(ra << 16);
    float r1 = __uint_as_float(ra & 0xFFFF0000u);
    a.x = fmaf(x0 * r0, sc, a.x);
    a.y = fmaf(x1 * r1, sc, a.y);
}

// ================= CSR build =================
__global__ __launch_bounds__(256) void hist_kernel(const int* __restrict__ ei,
                                                   int* __restrict__ cnt_in,
                                                   int* __restrict__ cnt_out) {
    int e = blockIdx.x * blockDim.x + threadIdx.x;
    if (e >= NE2) return;
    int row = ei[e];
    if (e < EHALF) atomicAdd(&cnt_in[row], 1);
    else           atomicAdd(&cnt_out[row], 1);
}

__global__ __launch_bounds__(256) void scan1_kernel(const int* __restrict__ cnt_in,
                                                    const int* __restrict__ cnt_out,
                                                    int* __restrict__ rp_in, int* __restrict__ rp_out,
                                                    float* __restrict__ dv_in, float* __restrict__ dv_out,
                                                    int* __restrict__ bsum) {
    int half = blockIdx.y;
    const int* cnt = half ? cnt_out : cnt_in;
    int* rp  = half ? rp_out : rp_in;
    float* dv = half ? dv_out : dv_in;
    __shared__ int sm[256];
    int tid = threadIdx.x;
    int base = blockIdx.x * 1024 + tid * 4;
    int v[4];
#pragma unroll
    for (int j = 0; j < 4; ++j) { int i = base + j; v[j] = (i < N_ENT) ? cnt[i] : 0; }
    int tsum = v[0] + v[1] + v[2] + v[3];
    sm[tid] = tsum;
    __syncthreads();
    for (int off = 1; off < 256; off <<= 1) {
        int t = (tid >= off) ? sm[tid - off] : 0;
        __syncthreads();
        sm[tid] += t;
        __syncthreads();
    }
    int run = sm[tid] - tsum;
#pragma unroll
    for (int j = 0; j < 4; ++j) {
        int i = base + j;
        if (i < N_ENT) {
            rp[i] = run;
            dv[i] = v[j] > 0 ? rsqrtf((float)v[j]) : 0.0f;
        }
        run += v[j];
    }
    if (tid == 255) bsum[half * 98 + blockIdx.x] = sm[255];
}

// scan of 98 block sums per half + zero BN stat accumulators
__global__ void scan2_kernel(int* __restrict__ bsum, float* __restrict__ stats) {
    int tid = threadIdx.x;
    stats[tid]       = 0.f;   // colsum
    stats[tid + 256] = 0.f;   // colsumsq
    if (tid < 2) {
        int run = 0;
        for (int b = 0; b < 98; ++b) { int t = bsum[tid * 98 + b]; bsum[tid * 98 + b] = run; run += t; }
    }
}

__global__ __launch_bounds__(256) void scan3_kernel(int* __restrict__ rp_in, int* __restrict__ rp_out,
                                                    int* __restrict__ cnt_in, int* __restrict__ cnt_out,
                                                    const int* __restrict__ bsum) {
    int half = blockIdx.y;
    int* rp  = half ? rp_out : rp_in;
    int* cnt = half ? cnt_out : cnt_in;
    int add = bsum[half * 98 + blockIdx.x];
    int base = blockIdx.x * 1024 + threadIdx.x * 4;
#pragma unroll
    for (int j = 0; j < 4; ++j) {
        int i = base + j;
        if (i < N_ENT) { int t = rp[i] + add; rp[i] = t; cnt[i] = t; }
    }
    if (blockIdx.x == 0 && threadIdx.x == 0) rp[N_ENT] = EHALF;
}

// packed scatter: el[p] = { (col<<8)|type , norm_scale_bits }  (8B records)
__global__ __launch_bounds__(256) void scatterp2_kernel(const int* __restrict__ ei,
                                                        const int* __restrict__ et,
                                                        const float* __restrict__ dv_in,
                                                        const float* __restrict__ dv_out,
                                                        int* __restrict__ cur_in, int* __restrict__ cur_out,
                                                        uint2* __restrict__ el_in, uint2* __restrict__ el_out) {
    int e = blockIdx.x * blockDim.x + threadIdx.x;
    if (e >= NE2) return;
    int row = ei[e];
    int col = ei[NE2 + e];
    unsigned pk = ((unsigned)col << 8) | (unsigned)et[e];
    if (e < EHALF) {
        float sc = dv_in[row] * dv_in[col];
        int p = atomicAdd(&cur_in[row], 1);
        el_in[p] = make_uint2(pk, __float_as_uint(sc));
    } else {
        float sc = dv_out[row] * dv_out[col];
        int p = atomicAdd(&cur_out[row], 1);
        el_out[p] = make_uint2(pk, __float_as_uint(sc));
    }
}

// legacy scatter (mid fallback)
__global__ __launch_bounds__(256) void scatter_kernel(const int* __restrict__ ei,
                                                      int* __restrict__ cur_in, int* __restrict__ cur_out,
                                                      int* __restrict__ el_in, int* __restrict__ el_out) {
    int e = blockIdx.x * blockDim.x + threadIdx.x;
    if (e >= NE2) return;
    int row = ei[e];
    if (e < EHALF) { int p = atomicAdd(&cur_in[row], 1);  el_in[p]  = e; }
    else           { int p = atomicAdd(&cur_out[row], 1); el_out[p] = e; }
}

// ============ prep: x/rel -> bf16, wT build, rel_out GEMM, x16 pad zero ========
#define PB_CONVX  25000              // N_ENT*D/4/256
#define PB_CONVR  (PB_CONVX + 50)    // NREL*D/4/256
#define PB_WCONV  (PB_CONVR + 256)
#define PB_RELG   (PB_WCONV + 200)
#define PB_PADS   (PB_RELG + 24)     // x16 pad: (MPAD-N_ENT)*D/4/256 = 24 blocks
__global__ __launch_bounds__(256) void prep_kernel(
        const float* __restrict__ x, const float* __restrict__ rel,
        const float* __restrict__ w_in, const float* __restrict__ w_out,
        const float* __restrict__ w_loop, const float* __restrict__ lrel,
        const float* __restrict__ w_rel,
        ushort* __restrict__ x16, ushort* __restrict__ rel16,
        ushort* __restrict__ wT, float* __restrict__ rel_out) {
    int b = blockIdx.x, tid = threadIdx.x;
    if (b < PB_CONVX) {
        int i = b * 256 + tid;
        float4 v = ((const float4*)x)[i];
        ushort4 o; o.x = f2b(v.x); o.y = f2b(v.y); o.z = f2b(v.z); o.w = f2b(v.w);
        ((ushort4*)x16)[i] = o;
    } else if (b < PB_CONVR) {
        int i = (b - PB_CONVX) * 256 + tid;
        float4 v = ((const float4*)rel)[i];
        ushort4 o; o.x = f2b(v.x); o.y = f2b(v.y); o.z = f2b(v.z); o.w = f2b(v.w);
        ((ushort4*)rel16)[i] = o;
    } else if (b < PB_WCONV) {
        int n = b - PB_CONVR;
        int k = tid;
        wT[(size_t)n * 768 + 0   + k] = f2b(w_in [k * 256 + n]);
        wT[(size_t)n * 768 + 256 + k] = f2b(w_out[k * 256 + n]);
        wT[(size_t)n * 768 + 512 + k] = f2b(w_loop[k * 256 + n] * lrel[k]);
    } else if (b < PB_RELG) {
        int r = b - PB_WCONV;
        int c = tid;
        float a = 0.f;
        for (int k = 0; k < 256; ++k)
            a = fmaf(rel[r * 256 + k], w_rel[k * 256 + c], a);
        rel_out[r * 256 + c] = a;
    } else {
        int i = (b - PB_RELG) * 256 + tid;     // [0,6144) ushort4s = (MPAD-N_ENT)*D
        ((ushort4*)(x16 + (size_t)N_ENT * D))[i] = (ushort4){0, 0, 0, 0};
    }
}

// ============ MERGED: aggregate (LDS panel) + GEMM + BN partials ==============
// 782 blocks x 512 thr. Per block: 128 entities. Panel P[128][256] bf16 in LDS
// with 16B-granule XOR swizzle (write g=(lane>>1)^(row&7), read g=(kt*4+kg)^(row&7)).
__global__ __launch_bounds__(512) void fused_all_kernel(
        const int* __restrict__ rp_in, const uint2* __restrict__ el_in,
        const int* __restrict__ rp_out, const uint2* __restrict__ el_out,
        const ushort* __restrict__ x16, const ushort* __restrict__ rel16,
        const ushort* __restrict__ wT, float* __restrict__ C,
        float* __restrict__ colsum, float* __restrict__ colsumsq) {
    __shared__ ushort P[128 * 256];          // 64 KB
    int tid  = threadIdx.x;
    int row0 = blockIdx.x * 128;
    int w = tid >> 6, lane = tid & 63;
    int wr = w >> 2, wc = w & 3;             // 2 row-groups x 4 col-groups
    int r16 = lane & 15, kg = lane >> 4, kg8 = kg * 8;

    const ushort* xl = x16   + lane * 4;
    const ushort* rl = rel16 + lane * 4;

    f32x4 acc[4][4];
#pragma unroll
    for (int mi = 0; mi < 4; ++mi)
#pragma unroll
        for (int ni = 0; ni < 4; ++ni)
            acc[mi][ni] = (f32x4){0.f, 0.f, 0.f, 0.f};

    int wg  = lane >> 1;                     // write granule (pre-swizzle)
    int whf = (lane & 1) << 2;               // 8B half within granule (ushorts)

    auto aggPhase = [&](const int* __restrict__ rp, const uint2* __restrict__ el) {
#pragma unroll 1
        for (int i = 0; i < 16; ++i) {
            int eloc = w * 16 + i;
            int e = row0 + eloc;
            float2 a01 = {0.f, 0.f}, a23 = {0.f, 0.f};
            if (e < N_ENT) {
                int s = rp[e], eend = rp[e + 1];
                int p = s;
                for (; p + 4 <= eend; p += 4) {
                    uint2 r0 = el[p], r1 = el[p + 1], r2 = el[p + 2], r3 = el[p + 3];
                    uint2 x0 = *(const uint2*)(xl + (size_t)(r0.x >> 8) * 256);
                    uint2 v0 = *(const uint2*)(rl + (size_t)(r0.x & 255u) * 256);
                    uint2 x1 = *(const uint2*)(xl + (size_t)(r1.x >> 8) * 256);
                    uint2 v1 = *(const uint2*)(rl + (size_t)(r1.x & 255u) * 256);
                    uint2 x2 = *(const uint2*)(xl + (size_t)(r2.x >> 8) * 256);
                    uint2 v2 = *(const uint2*)(rl + (size_t)(r2.x & 255u) * 256);
                    uint2 x3 = *(const uint2*)(xl + (size_t)(r3.x >> 8) * 256);
                    uint2 v3 = *(const uint2*)(rl + (size_t)(r3.x & 255u) * 256);
                    float s0 = __uint_as_float(r0.y), s1 = __uint_as_float(r1.y);
                    float s2 = __uint_as_float(r2.y), s3 = __uint_as_float(r3.y);
                    bacc(x0.x, v0.x, s0, a01); bacc(x0.y, v0.y, s0, a23);
                    bacc(x1.x, v1.x, s1, a01); bacc(x1.y, v1.y, s1, a23);
                    bacc(x2.x, v2.x, s2, a01); bacc(x2.y, v2.y, s2, a23);
                    bacc(x3.x, v3.x, s3, a01); bacc(x3.y, v3.y, s3, a23);
                }
                for (; p < eend; ++p) {
                    uint2 rr = el[p];
                    uint2 xv = *(const uint2*)(xl + (size_t)(rr.x >> 8) * 256);
                    uint2 rv = *(const uint2*)(rl + (size_t)(rr.x & 255u) * 256);
                    float sc = __uint_as_float(rr.y);
                    bacc(xv.x, rv.x, sc, a01); bacc(xv.y, rv.y, sc, a23);
                }
            }
            ushort4 o;
            o.x = f2b(a01.x); o.y = f2b(a01.y); o.z = f2b(a23.x); o.w = f2b(a23.y);
            *(ushort4*)&P[eloc * 256 + ((wg ^ (eloc & 7)) << 3) + whf] = o;
        }
    };

    auto gemmP = [&](int kb) {               // A from LDS panel; B k-base kb
#pragma unroll
        for (int kt = 0; kt < 8; ++kt) {
            int k0 = kt * 32;
            bf16x8 af[4], bf[4];
#pragma unroll
            for (int mi = 0; mi < 4; ++mi) {
                int row = wr * 64 + mi * 16 + r16;
                af[mi] = *(const bf16x8*)&P[row * 256 + (((kt * 4 + kg) ^ (row & 7)) << 3)];
            }
#pragma unroll
            for (int ni = 0; ni < 4; ++ni)
                bf[ni] = *(const bf16x8*)&wT[(size_t)(wc * 64 + ni * 16 + r16) * 768 + kb + k0 + kg8];
#pragma unroll
            for (int mi = 0; mi < 4; ++mi)
#pragma unroll
                for (int ni = 0; ni < 4; ++ni)
                    acc[mi][ni] = __builtin_amdgcn_mfma_f32_16x16x32_bf16(af[mi], bf[ni], acc[mi][ni], 0, 0, 0);
        }
    };

    aggPhase(rp_in, el_in);
    __syncthreads();
    gemmP(0);
    __syncthreads();
    aggPhase(rp_out, el_out);
    __syncthreads();
    gemmP(256);

    // x-segment: A streamed from global (k-contiguous), K = 512..767
#pragma unroll
    for (int kt = 0; kt < 8; ++kt) {
        int k0 = kt * 32;
        bf16x8 af[4], bf[4];
#pragma unroll
        for (int mi = 0; mi < 4; ++mi)
            af[mi] = *(const bf16x8*)&x16[(size_t)(row0 + wr * 64 + mi * 16 + r16) * 256 + k0 + kg8];
#pragma unroll
        for (int ni = 0; ni < 4; ++ni)
            bf[ni] = *(const bf16x8*)&wT[(size_t)(wc * 64 + ni * 16 + r16) * 768 + 512 + k0 + kg8];
#pragma unroll
        for (int mi = 0; mi < 4; ++mi)
#pragma unroll
            for (int ni = 0; ni < 4; ++ni)
                acc[mi][ni] = __builtin_amdgcn_mfma_f32_16x16x32_bf16(af[mi], bf[ni], acc[mi][ni], 0, 0, 0);
    }

    // ---- C store ----
#pragma unroll
    for (int mi = 0; mi < 4; ++mi) {
        int r = row0 + wr * 64 + mi * 16 + kg * 4;
#pragma unroll
        for (int ni = 0; ni < 4; ++ni) {
            int c = wc * 64 + ni * 16 + r16;
#pragma unroll
            for (int j = 0; j < 4; ++j) {
                int rr = r + j;
                if (rr < N_ENT) C[(size_t)rr * 256 + c] = acc[mi][ni][j];
            }
        }
    }

    // ---- BN raw partial sums (pad rows produce zeros) ----
#pragma unroll
    for (int ni = 0; ni < 4; ++ni) {
        float s = 0.f, ss = 0.f;
#pragma unroll
        for (int mi = 0; mi < 4; ++mi)
#pragma unroll
            for (int j = 0; j < 4; ++j) {
                float v = acc[mi][ni][j];
                s += v; ss += v * v;
            }
        s += __shfl_xor(s, 16); ss += __shfl_xor(ss, 16);
        s += __shfl_xor(s, 32); ss += __shfl_xor(ss, 32);
        if (kg == 0) {
            int c = wc * 64 + ni * 16 + r16;
            atomicAdd(&colsum[c], s);
            atomicAdd(&colsumsq[c], ss);
        }
    }
}

// ============ mid-fallback kernels (f32 gathers + reg-staged GEMM) ============
__global__ __launch_bounds__(256) void agg_csr16_kernel(
        const int* __restrict__ rp, const int* __restrict__ elist,
        const int* __restrict__ colidx, const int* __restrict__ et,
        const float* __restrict__ dinv, const float* __restrict__ x,
        const float* __restrict__ rel, ushort* __restrict__ agg) {
    int wid  = (blockIdx.x * blockDim.x + threadIdx.x) >> 6;
    int lane = threadIdx.x & 63;
    if (wid >= N_ENT) return;
    int s = rp[wid], eend = rp[wid + 1];
    float dr = dinv[wid];
    float4 acc = make_float4(0.f, 0.f, 0.f, 0.f);
    int e = (s < eend) ? elist[s] : 0;
    for (int p = s; p < eend; ++p) {
        int c = colidx[e];
        int t = et[e];
        int enext = (p + 1 < eend) ? elist[p + 1] : 0;
        float sc = dr * dinv[c];
        float4 xv = *(const float4*)(x   + (size_t)c * D + lane * 4);
        float4 rv = *(const float4*)(rel + (size_t)t * D + lane * 4);
        acc.x = fmaf(xv.x * rv.x, sc, acc.x);
        acc.y = fmaf(xv.y * rv.y, sc, acc.y);
        acc.z = fmaf(xv.z * rv.z, sc, acc.z);
        acc.w = fmaf(xv.w * rv.w, sc, acc.w);
        e = enext;
    }
    ushort4 o;
    o.x = f2b(acc.x); o.y = f2b(acc.y); o.z = f2b(acc.z); o.w = f2b(acc.w);
    *(ushort4*)(agg + (size_t)wid * D + lane * 4) = o;
}

__global__ __launch_bounds__(256) void wconv_kernel(const float* __restrict__ w_in,
                                                    const float* __restrict__ w_out,
                                                    const float* __restrict__ w_loop,
                                                    ushort* __restrict__ wT) {
    int n = blockIdx.x;
    int k = threadIdx.x;
    wT[(size_t)n * 768 + 0   + k] = f2b(w_in [k * 256 + n]);
    wT[(size_t)n * 768 + 256 + k] = f2b(w_out[k * 256 + n]);
    wT[(size_t)n * 768 + 512 + k] = f2b(w_loop[k * 256 + n]);
}

__global__ __launch_bounds__(256) void fused_gemm_fb_kernel(
        const ushort* __restrict__ Ain, const ushort* __restrict__ Aout,
        const float* __restrict__ xf, const float* __restrict__ lrel,
        const ushort* __restrict__ wT, float* __restrict__ C) {
    __shared__ ushort As[2][128 * 40];
    __shared__ ushort Bs[2][128 * 40];
    int tid  = threadIdx.x;
    int row0 = blockIdx.x * 128;
    int col0 = blockIdx.y * 128;
    int srow = tid >> 1, hb = tid & 1;
    int w    = tid >> 6, lane = tid & 63;
    int wr   = w >> 1,  wc = w & 1;
    int r16  = lane & 15, kg = lane >> 4;

    f32x4 acc[4][4];
#pragma unroll
    for (int mi = 0; mi < 4; ++mi)
#pragma unroll
        for (int ni = 0; ni < 4; ++ni)
            acc[mi][ni] = (f32x4){0.f, 0.f, 0.f, 0.f};

    auto stage = [&](int kt, int buf) {
        int k0 = kt * 32;
        int seg = k0 >> 8;
        int kl  = (k0 & 255) + hb * 16;
        ushort* Ad = &As[buf][srow * 40 + hb * 16];
        if (seg < 2) {
            const ushort* src = (seg ? Aout : Ain) + (size_t)(row0 + srow) * 256 + kl;
            *(us8*)Ad       = *(const us8*)src;
            *(us8*)(Ad + 8) = *(const us8*)(src + 8);
        } else {
            int gr = row0 + srow;
            us8 pa, pb;
            if (gr < N_ENT) {
                const float* src = xf + (size_t)gr * 256 + kl;
                const float* ls  = lrel + kl;
#pragma unroll
                for (int j = 0; j < 8; ++j) {
                    pa[j] = (short)f2b(src[j] * ls[j]);
                    pb[j] = (short)f2b(src[8 + j] * ls[8 + j]);
                }
            } else {
#pragma unroll
                for (int j = 0; j < 8; ++j) { pa[j] = 0; pb[j] = 0; }
            }
            *(us8*)Ad       = pa;
            *(us8*)(Ad + 8) = pb;
        }
        ushort* Bd = &Bs[buf][srow * 40 + hb * 16];
        const ushort* bsrc = wT + (size_t)(col0 + srow) * 768 + k0 + hb * 16;
        *(us8*)Bd       = *(const us8*)bsrc;
        *(us8*)(Bd + 8) = *(const us8*)(bsrc + 8);
    };

    stage(0, 0);
    __syncthreads();
    for (int kt = 0; kt < 24; ++kt) {
        int cur = kt & 1;
        if (kt + 1 < 24) stage(kt + 1, cur ^ 1);
        const ushort* Ab = &As[cur][(wr * 64 + r16) * 40 + kg * 8];
        const ushort* Bb = &Bs[cur][(wc * 64 + r16) * 40 + kg * 8];
        bf16x8 af[4], bfr[4];
#pragma unroll
        for (int i = 0; i < 4; ++i) {
            af[i]  = *(const bf16x8*)(Ab + i * 640);
            bfr[i] = *(const bf16x8*)(Bb + i * 640);
        }
#pragma unroll
        for (int mi = 0; mi < 4; ++mi)
#pragma unroll
            for (int ni = 0; ni < 4; ++ni)
                acc[mi][ni] = __builtin_amdgcn_mfma_f32_16x16x32_bf16(af[mi], bfr[ni], acc[mi][ni], 0, 0, 0);
        __syncthreads();
    }

#pragma unroll
    for (int mi = 0; mi < 4; ++mi) {
        int r = row0 + wr * 64 + mi * 16 + kg * 4;
#pragma unroll
        for (int ni = 0; ni < 4; ++ni) {
            int c = col0 + wc * 64 + ni * 16 + r16;
#pragma unroll
            for (int j = 0; j < 4; ++j) {
                int rr = r + j;
                if (rr < N_ENT) C[(size_t)rr * 256 + c] = acc[mi][ni][j];
            }
        }
    }
}

// ---------------- BatchNorm ----------------
__global__ __launch_bounds__(256) void bn_stats_kernel(
        const float* __restrict__ out, const float* __restrict__ bias,
        float* __restrict__ colsum, float* __restrict__ colsumsq) {
    int c  = threadIdx.x;
    int r0 = blockIdx.x * 64;
    float b = bias[c];
    float s = 0.f, sq = 0.f;
    int rend = min(r0 + 64, N_ENT);
    for (int r = r0; r < rend; ++r) {
        float v = out[(size_t)r * 256 + c] * (1.f / 3.f) + b;
        s += v; sq += v * v;
    }
    atomicAdd(&colsum[c], s);
    atomicAdd(&colsumsq[c], sq);
}

template<bool RAW>
__global__ void bn_finalize_kernel(const float* __restrict__ colsum, const float* __restrict__ colsumsq,
                                   const float* __restrict__ bias, const float* __restrict__ gamma,
                                   const float* __restrict__ beta,
                                   float* __restrict__ colA, float* __restrict__ colB) {
    int c = threadIdx.x;
    float invN = 1.f / N_ENT;
    float mean, var;
    if (RAW) {
        float Er  = colsum[c] * invN;
        float Er2 = colsumsq[c] * invN;
        float b = bias[c];
        mean = Er * (1.f / 3.f) + b;
        var  = Er2 * (1.f / 9.f) + 2.f * b * Er * (1.f / 3.f) + b * b - mean * mean;
    } else {
        mean = colsum[c] * invN;
        var  = colsumsq[c] * invN - mean * mean;
    }
    float sc = rsqrtf(var + BN_EPS) * gamma[c];
    colA[c] = sc * (1.f / 3.f);
    colB[c] = (bias[c] - mean) * sc + beta[c];
}

__global__ __launch_bounds__(256) void bn_apply_kernel(
        float* __restrict__ out, const float* __restrict__ colA, const float* __restrict__ colB) {
    size_t i4 = (size_t)blockIdx.x * 256 + threadIdx.x;
    float4 v = ((const float4*)out)[i4];
    int c4 = (int)(i4 & 63) * 4;
    v.x = v.x * colA[c4 + 0] + colB[c4 + 0];
    v.y = v.y * colA[c4 + 1] + colB[c4 + 1];
    v.z = v.z * colA[c4 + 2] + colB[c4 + 2];
    v.w = v.w * colA[c4 + 3] + colB[c4 + 3];
    ((float4*)out)[i4] = v;
}

__global__ __launch_bounds__(256) void relgemm_kernel(
        const float* __restrict__ rel, const float* __restrict__ w, float* __restrict__ out) {
    int r = blockIdx.x;
    int c = threadIdx.x;
    float acc = 0.f;
    for (int k = 0; k < 256; ++k)
        acc = fmaf(rel[r * 256 + k], w[k * 256 + c], acc);
    out[r * 256 + c] = acc;
}

extern "C" void kernel_launch(void* const* d_in, const int* in_sizes, int n_in,
                              void* d_out, int out_size, void* d_ws, size_t ws_size,
                              hipStream_t stream) {
    const float* x        = (const float*)d_in[0];
    const int*   ei       = (const int*)d_in[1];
    const int*   et       = (const int*)d_in[2];
    const float* rel      = (const float*)d_in[3];
    const float* w_loop   = (const float*)d_in[4];
    const float* w_in     = (const float*)d_in[5];
    const float* w_out    = (const float*)d_in[6];
    const float* w_rel    = (const float*)d_in[7];
    const float* loop_rel = (const float*)d_in[8];
    const float* bias     = (const float*)d_in[9];
    const float* gamma    = (const float*)d_in[10];
    const float* beta     = (const float*)d_in[11];

    float* out     = (float*)d_out;
    float* rel_out = out + (size_t)N_ENT * D;
    const int* colidx = ei + NE2;

    // ---- workspace layout ----
    char* ws = (char*)d_ws;
    size_t off = 0;
    int* rp_in    = (int*)(ws + off); off += 400416;
    int* rp_out   = (int*)(ws + off); off += 400416;
    float* dv_in  = (float*)(ws + off); off += 400416;
    float* dv_out = (float*)(ws + off); off += 400416;
    int* cnt_in   = (int*)(ws + off); off += 400416;
    int* cnt_out  = (int*)(ws + off); off += 400416;
    uint2* el2_in  = (uint2*)(ws + off); off += (size_t)EHALF * 8;
    uint2* el2_out = (uint2*)(ws + off); off += (size_t)EHALF * 8;
    ushort* wT    = (ushort*)(ws + off); off += 768 * 256 * 2;
    float* stats  = (float*)(ws + off); off += 8192;
    size_t off_x16 = off;
    ushort* x16   = (ushort*)(ws + off); off += (size_t)MPAD * D * 2;
    ushort* rel16 = (ushort*)(ws + off); off += (size_t)NREL * D * 2;
    size_t needed_full = off;
    // fallback agg arrays alias the x16/rel16 region (not used concurrently)
    ushort* agg_in16_fb  = (ushort*)(ws + off_x16);
    ushort* agg_out16_fb = agg_in16_fb + (size_t)MPAD * D;
    size_t needed_mid = off_x16 + (size_t)MPAD * D * 2 * 2;

    float* colsum = stats, *colsumsq = stats + 256;
    float* colA = stats + 512, *colB = stats + 768;
    int* bsum = (int*)(stats + 1024);

    if (ws_size >= needed_full) {
        // ======== merged path ========
        hipMemsetAsync(cnt_in, 0, 2 * 400416, stream);

        hist_kernel<<<(NE2 + 255) / 256, 256, 0, stream>>>(ei, cnt_in, cnt_out);
        scan1_kernel<<<dim3(98, 2), 256, 0, stream>>>(cnt_in, cnt_out, rp_in, rp_out, dv_in, dv_out, bsum);
        scan2_kernel<<<1, 256, 0, stream>>>(bsum, stats);
        scan3_kernel<<<dim3(98, 2), 256, 0, stream>>>(rp_in, rp_out, cnt_in, cnt_out, bsum);
        scatterp2_kernel<<<(NE2 + 255) / 256, 256, 0, stream>>>(ei, et, dv_in, dv_out,
                                                                cnt_in, cnt_out, el2_in, el2_out);
        prep_kernel<<<PB_PADS, 256, 0, stream>>>(x, rel, w_in, w_out, w_loop, loop_rel, w_rel,
                                                 x16, rel16, wT, rel_out);

        fused_all_kernel<<<MPAD / 128, 512, 0, stream>>>(
            rp_in, el2_in, rp_out, el2_out, x16, rel16, wT, out, colsum, colsumsq);

        bn_finalize_kernel<true><<<1, 256, 0, stream>>>(colsum, colsumsq, bias, gamma, beta, colA, colB);
        bn_apply_kernel<<<(N_ENT * 64) / 256, 256, 0, stream>>>(out, colA, colB);
    } else if (ws_size >= needed_mid) {
        // ======== mid fallback: f32 gathers, separate bn_stats ========
        int* el_in  = (int*)el2_in;
        int* el_out = el_in + EHALF;
        hipMemsetAsync(cnt_in, 0, 2 * 400416, stream);
        hist_kernel<<<(NE2 + 255) / 256, 256, 0, stream>>>(ei, cnt_in, cnt_out);
        scan1_kernel<<<dim3(98, 2), 256, 0, stream>>>(cnt_in, cnt_out, rp_in, rp_out, dv_in, dv_out, bsum);
        scan2_kernel<<<1, 256, 0, stream>>>(bsum, stats);
        scan3_kernel<<<dim3(98, 2), 256, 0, stream>>>(rp_in, rp_out, cnt_in, cnt_out, bsum);
        scatter_kernel<<<(NE2 + 255) / 256, 256, 0, stream>>>(ei, cnt_in, cnt_out, el_in, el_out);
        wconv_kernel<<<256, 256, 0, stream>>>(w_in, w_out, w_loop, wT);

        agg_csr16_kernel<<<(N_ENT * 64 + 255) / 256, 256, 0, stream>>>(
            rp_in, el_in, colidx, et, dv_in, x, rel, agg_in16_fb);
        agg_csr16_kernel<<<(N_ENT * 64 + 255) / 256, 256, 0, stream>>>(
            rp_out, el_out, colidx, et, dv_out, x, rel, agg_out16_fb);

        // zero pad rows of agg arrays (bn_stats only reads < N_ENT, gemm reads pads)
        hipMemsetAsync(agg_in16_fb  + (size_t)N_ENT * D, 0, (MPAD - N_ENT) * D * 2, stream);
        hipMemsetAsync(agg_out16_fb + (size_t)N_ENT * D, 0, (MPAD - N_ENT) * D * 2, stream);

        fused_gemm_fb_kernel<<<dim3(MPAD / 128, 2), 256, 0, stream>>>(
            agg_in16_fb, agg_out16_fb, x, loop_rel, wT, out);

        bn_stats_kernel<<<(N_ENT + 63) / 64, 256, 0, stream>>>(out, bias, colsum, colsumsq);
        bn_finalize_kernel<false><<<1, 256, 0, stream>>>(colsum, colsumsq, bias, gamma, beta, colA, colB);
        bn_apply_kernel<<<(N_ENT * 64) / 256, 256, 0, stream>>>(out, colA, colB);
        relgemm_kernel<<<NREL, 256, 0, stream>>>(rel, w_rel, rel_out);
    }
}

// Round 11
// 357.802 us; speedup vs baseline: 1.7850x; 1.7850x over previous
//
#include <hip/hip_runtime.h>

#define N_ENT  100000
#define MPAD   100096           // 782 * 128
#define EHALF  500000
#define NE2    1000000
#define D      256
#define NREL   200
#define BN_EPS 1e-5f

typedef __attribute__((ext_vector_type(8))) short  bf16x8;
typedef __attribute__((ext_vector_type(8))) ushort us8;
typedef __attribute__((ext_vector_type(4))) float  f32x4;

__device__ __forceinline__ ushort f2b(float f) {
    unsigned u = __float_as_uint(f);
    return (ushort)((u + 0x7fffu + ((u >> 16) & 1u)) >> 16);
}
__device__ __forceinline__ float b2f(ushort u) {
    return __uint_as_float((unsigned)u << 16);
}

// async global->LDS, 16B per lane; lds dest wave-uniform base (+lane*16 implicit)
__device__ __forceinline__ void gload16(const void* g, void* l) {
    __builtin_amdgcn_global_load_lds((__attribute__((address_space(1))) void*)g,
                                     (__attribute__((address_space(3))) void*)l, 16, 0, 0);
}

// bf16-pair (one dword) elementwise product accumulate: a += (x .* r) * sc
__device__ __forceinline__ void bacc(unsigned xa, unsigned ra, float sc, float2& a) {
    float x0 = __uint_as_float(xa << 16);
    float x1 = __uint_as_float(xa & 0xFFFF0000u);
    float r0 = __uint_as_float(ra << 16);
    float r1 = __uint_as_float(ra & 0xFFFF0000u);
    a.x = fmaf(x0 * r0, sc, a.x);
    a.y = fmaf(x1 * r1, sc, a.y);
}

// ================= CSR build =================
__global__ __launch_bounds__(256) void hist_kernel(const int* __restrict__ ei,
                                                   int* __restrict__ cnt_in,
                                                   int* __restrict__ cnt_out) {
    int e = blockIdx.x * blockDim.x + threadIdx.x;
    if (e >= NE2) return;
    int row = ei[e];
    if (e < EHALF) atomicAdd(&cnt_in[row], 1);
    else           atomicAdd(&cnt_out[row], 1);
}

__global__ __launch_bounds__(256) void scan1_kernel(const int* __restrict__ cnt_in,
                                                    const int* __restrict__ cnt_out,
                                                    int* __restrict__ rp_in, int* __restrict__ rp_out,
                                                    float* __restrict__ dv_in, float* __restrict__ dv_out,
                                                    int* __restrict__ bsum) {
    int half = blockIdx.y;
    const int* cnt = half ? cnt_out : cnt_in;
    int* rp  = half ? rp_out : rp_in;
    float* dv = half ? dv_out : dv_in;
    __shared__ int sm[256];
    int tid = threadIdx.x;
    int base = blockIdx.x * 1024 + tid * 4;
    int v[4];
#pragma unroll
    for (int j = 0; j < 4; ++j) { int i = base + j; v[j] = (i < N_ENT) ? cnt[i] : 0; }
    int tsum = v[0] + v[1] + v[2] + v[3];
    sm[tid] = tsum;
    __syncthreads();
    for (int off = 1; off < 256; off <<= 1) {
        int t = (tid >= off) ? sm[tid - off] : 0;
        __syncthreads();
        sm[tid] += t;
        __syncthreads();
    }
    int run = sm[tid] - tsum;
#pragma unroll
    for (int j = 0; j < 4; ++j) {
        int i = base + j;
        if (i < N_ENT) {
            rp[i] = run;
            dv[i] = v[j] > 0 ? rsqrtf((float)v[j]) : 0.0f;
        }
        run += v[j];
    }
    if (tid == 255) bsum[half * 98 + blockIdx.x] = sm[255];
}

// scan of 98 block sums per half + zero BN stat accumulators
__global__ void scan2_kernel(int* __restrict__ bsum, float* __restrict__ stats) {
    int tid = threadIdx.x;
    stats[tid]       = 0.f;   // colsum
    stats[tid + 256] = 0.f;   // colsumsq
    if (tid < 2) {
        int run = 0;
        for (int b = 0; b < 98; ++b) { int t = bsum[tid * 98 + b]; bsum[tid * 98 + b] = run; run += t; }
    }
}

__global__ __launch_bounds__(256) void scan3_kernel(int* __restrict__ rp_in, int* __restrict__ rp_out,
                                                    int* __restrict__ cnt_in, int* __restrict__ cnt_out,
                                                    const int* __restrict__ bsum) {
    int half = blockIdx.y;
    int* rp  = half ? rp_out : rp_in;
    int* cnt = half ? cnt_out : cnt_in;
    int add = bsum[half * 98 + blockIdx.x];
    int base = blockIdx.x * 1024 + threadIdx.x * 4;
#pragma unroll
    for (int j = 0; j < 4; ++j) {
        int i = base + j;
        if (i < N_ENT) { int t = rp[i] + add; rp[i] = t; cnt[i] = t; }
    }
    if (blockIdx.x == 0 && threadIdx.x == 0) rp[N_ENT] = EHALF;
}

// packed scatter: el[p] = { (col<<8)|type , norm_scale_bits }  (8B records)
__global__ __launch_bounds__(256) void scatterp2_kernel(const int* __restrict__ ei,
                                                        const int* __restrict__ et,
                                                        const float* __restrict__ dv_in,
                                                        const float* __restrict__ dv_out,
                                                        int* __restrict__ cur_in, int* __restrict__ cur_out,
                                                        uint2* __restrict__ el_in, uint2* __restrict__ el_out) {
    int e = blockIdx.x * blockDim.x + threadIdx.x;
    if (e >= NE2) return;
    int row = ei[e];
    int col = ei[NE2 + e];
    unsigned pk = ((unsigned)col << 8) | (unsigned)et[e];
    if (e < EHALF) {
        float sc = dv_in[row] * dv_in[col];
        int p = atomicAdd(&cur_in[row], 1);
        el_in[p] = make_uint2(pk, __float_as_uint(sc));
    } else {
        float sc = dv_out[row] * dv_out[col];
        int p = atomicAdd(&cur_out[row], 1);
        el_out[p] = make_uint2(pk, __float_as_uint(sc));
    }
}

// legacy scatter (mid fallback)
__global__ __launch_bounds__(256) void scatter_kernel(const int* __restrict__ ei,
                                                      int* __restrict__ cur_in, int* __restrict__ cur_out,
                                                      int* __restrict__ el_in, int* __restrict__ el_out) {
    int e = blockIdx.x * blockDim.x + threadIdx.x;
    if (e >= NE2) return;
    int row = ei[e];
    if (e < EHALF) { int p = atomicAdd(&cur_in[row], 1);  el_in[p]  = e; }
    else           { int p = atomicAdd(&cur_out[row], 1); el_out[p] = e; }
}

// ===== fat kernel: hist + x/rel->bf16 + wT + rel_out GEMM + pad zero =====
#define HB        3907               // ceil(NE2/256)
#define PB_CONVX  (HB + 25000)       // N_ENT*D/4/256
#define PB_CONVR  (PB_CONVX + 50)
#define PB_WCONV  (PB_CONVR + 256)
#define PB_RELG   (PB_WCONV + 200)
#define PB_END    (PB_RELG + 72)     // 3 arrays * 24 blocks of pad zeroing
__global__ __launch_bounds__(256) void histprep_kernel(
        const int* __restrict__ ei, int* __restrict__ cnt_in, int* __restrict__ cnt_out,
        const float* __restrict__ x, const float* __restrict__ rel,
        const float* __restrict__ w_in, const float* __restrict__ w_out,
        const float* __restrict__ w_loop, const float* __restrict__ lrel,
        const float* __restrict__ w_rel,
        ushort* __restrict__ x16, ushort* __restrict__ rel16,
        ushort* __restrict__ wT, float* __restrict__ rel_out,
        ushort* __restrict__ agg_in, ushort* __restrict__ agg_out) {
    int b = blockIdx.x, tid = threadIdx.x;
    if (b < HB) {
        int e = b * 256 + tid;
        if (e < NE2) {
            int row = ei[e];
            if (e < EHALF) atomicAdd(&cnt_in[row], 1);
            else           atomicAdd(&cnt_out[row], 1);
        }
    } else if (b < PB_CONVX) {
        int i = (b - HB) * 256 + tid;
        float4 v = ((const float4*)x)[i];
        ushort4 o; o.x = f2b(v.x); o.y = f2b(v.y); o.z = f2b(v.z); o.w = f2b(v.w);
        ((ushort4*)x16)[i] = o;
    } else if (b < PB_CONVR) {
        int i = (b - PB_CONVX) * 256 + tid;
        float4 v = ((const float4*)rel)[i];
        ushort4 o; o.x = f2b(v.x); o.y = f2b(v.y); o.z = f2b(v.z); o.w = f2b(v.w);
        ((ushort4*)rel16)[i] = o;
    } else if (b < PB_WCONV) {
        int n = b - PB_CONVR;
        int k = tid;
        wT[(size_t)n * 768 + 0   + k] = f2b(w_in [k * 256 + n]);
        wT[(size_t)n * 768 + 256 + k] = f2b(w_out[k * 256 + n]);
        wT[(size_t)n * 768 + 512 + k] = f2b(w_loop[k * 256 + n] * lrel[k]);
    } else if (b < PB_RELG) {
        int r = b - PB_WCONV;
        int c = tid;
        float a = 0.f;
        for (int k = 0; k < 256; ++k)
            a = fmaf(rel[r * 256 + k], w_rel[k * 256 + c], a);
        rel_out[r * 256 + c] = a;
    } else {
        int idx = b - PB_RELG;            // [0,72)
        int arr = idx / 24, blk = idx % 24;
        ushort* base = (arr == 0) ? agg_in : (arr == 1) ? agg_out : x16;
        int i = blk * 256 + tid;          // (MPAD-N_ENT)*D/4 = 6144 ushort4s
        ((ushort4*)(base + (size_t)N_ENT * D))[i] = (ushort4){0, 0, 0, 0};
    }
}

// ============ both-halves bf16 gather aggregation (one wave / entity) =========
__global__ __launch_bounds__(256) void agg2both_kernel(
        const int* __restrict__ rp_in, const uint2* __restrict__ el_in, ushort* __restrict__ agg_in,
        const int* __restrict__ rp_out, const uint2* __restrict__ el_out, ushort* __restrict__ agg_out,
        const ushort* __restrict__ x16, const ushort* __restrict__ rel16) {
    int wid  = (blockIdx.x * blockDim.x + threadIdx.x) >> 6;
    int lane = threadIdx.x & 63;
    if (wid >= N_ENT) return;
    const ushort* xl = x16   + lane * 4;
    const ushort* rl = rel16 + lane * 4;

    auto run = [&](const int* __restrict__ rp, const uint2* __restrict__ el,
                   ushort* __restrict__ agg) {
        int s = rp[wid], eend = rp[wid + 1];
        float2 a01 = {0.f, 0.f}, a23 = {0.f, 0.f};
        int p = s;
        for (; p + 4 <= eend; p += 4) {
            uint2 r0 = el[p], r1 = el[p + 1], r2 = el[p + 2], r3 = el[p + 3];
            uint2 x0 = *(const uint2*)(xl + (size_t)(r0.x >> 8) * 256);
            uint2 v0 = *(const uint2*)(rl + (size_t)(r0.x & 255u) * 256);
            uint2 x1 = *(const uint2*)(xl + (size_t)(r1.x >> 8) * 256);
            uint2 v1 = *(const uint2*)(rl + (size_t)(r1.x & 255u) * 256);
            uint2 x2 = *(const uint2*)(xl + (size_t)(r2.x >> 8) * 256);
            uint2 v2 = *(const uint2*)(rl + (size_t)(r2.x & 255u) * 256);
            uint2 x3 = *(const uint2*)(xl + (size_t)(r3.x >> 8) * 256);
            uint2 v3 = *(const uint2*)(rl + (size_t)(r3.x & 255u) * 256);
            float s0 = __uint_as_float(r0.y), s1 = __uint_as_float(r1.y);
            float s2 = __uint_as_float(r2.y), s3 = __uint_as_float(r3.y);
            bacc(x0.x, v0.x, s0, a01); bacc(x0.y, v0.y, s0, a23);
            bacc(x1.x, v1.x, s1, a01); bacc(x1.y, v1.y, s1, a23);
            bacc(x2.x, v2.x, s2, a01); bacc(x2.y, v2.y, s2, a23);
            bacc(x3.x, v3.x, s3, a01); bacc(x3.y, v3.y, s3, a23);
        }
        for (; p < eend; ++p) {
            uint2 rr = el[p];
            uint2 xv = *(const uint2*)(xl + (size_t)(rr.x >> 8) * 256);
            uint2 rv = *(const uint2*)(rl + (size_t)(rr.x & 255u) * 256);
            float sc = __uint_as_float(rr.y);
            bacc(xv.x, rv.x, sc, a01); bacc(xv.y, rv.y, sc, a23);
        }
        ushort4 o;
        o.x = f2b(a01.x); o.y = f2b(a01.y); o.z = f2b(a23.x); o.w = f2b(a23.y);
        *(ushort4*)(agg + (size_t)wid * D + lane * 4) = o;
    };

    run(rp_in, el_in, agg_in);
    run(rp_out, el_out, agg_out);
}

// ============ legacy f32-x aggregation (mid fallback) ============
__global__ __launch_bounds__(256) void agg_csr16_kernel(
        const int* __restrict__ rp, const int* __restrict__ elist,
        const int* __restrict__ colidx, const int* __restrict__ et,
        const float* __restrict__ dinv, const float* __restrict__ x,
        const float* __restrict__ rel, ushort* __restrict__ agg) {
    int wid  = (blockIdx.x * blockDim.x + threadIdx.x) >> 6;
    int lane = threadIdx.x & 63;
    if (wid >= N_ENT) return;
    int s = rp[wid], eend = rp[wid + 1];
    float dr = dinv[wid];
    float4 acc = make_float4(0.f, 0.f, 0.f, 0.f);
    int e = (s < eend) ? elist[s] : 0;
    for (int p = s; p < eend; ++p) {
        int c = colidx[e];
        int t = et[e];
        int enext = (p + 1 < eend) ? elist[p + 1] : 0;
        float sc = dr * dinv[c];
        float4 xv = *(const float4*)(x   + (size_t)c * D + lane * 4);
        float4 rv = *(const float4*)(rel + (size_t)t * D + lane * 4);
        acc.x = fmaf(xv.x * rv.x, sc, acc.x);
        acc.y = fmaf(xv.y * rv.y, sc, acc.y);
        acc.z = fmaf(xv.z * rv.z, sc, acc.z);
        acc.w = fmaf(xv.w * rv.w, sc, acc.w);
        e = enext;
    }
    ushort4 o;
    o.x = f2b(acc.x); o.y = f2b(acc.y); o.z = f2b(acc.z); o.w = f2b(acc.w);
    *(ushort4*)(agg + (size_t)wid * D + lane * 4) = o;
}

__global__ __launch_bounds__(256) void wconv_kernel(const float* __restrict__ w_in,
                                                    const float* __restrict__ w_out,
                                                    const float* __restrict__ w_loop,
                                                    ushort* __restrict__ wT) {
    int n = blockIdx.x;
    int k = threadIdx.x;
    wT[(size_t)n * 768 + 0   + k] = f2b(w_in [k * 256 + n]);
    wT[(size_t)n * 768 + 256 + k] = f2b(w_out[k * 256 + n]);
    wT[(size_t)n * 768 + 512 + k] = f2b(w_loop[k * 256 + n]);
}

// ===== full-N fused GEMM: C16 = bf16([Ain|Aout|x16] @ wT^T), + BN partials =====
// 782 blocks x 512 thr (8 waves = 2 row-groups x 4 col-groups). 128 rows x 256
// cols per block. Double-buffered LDS, global_load_lds w16 staging.
// C16 ALIASES Ain: each block reads only its own rows (all K-segments) before
// writing the same rows in the epilogue; rows are block-private. Safe.
__global__ __launch_bounds__(512) void gemm5_kernel(
        const ushort* __restrict__ Ain, const ushort* __restrict__ Aout,
        const ushort* __restrict__ X16p, const ushort* __restrict__ wT,
        ushort* __restrict__ C16, float* __restrict__ colsum, float* __restrict__ colsumsq) {
    __shared__ ushort As[2][128 * 32];   // 8 KB each
    __shared__ ushort Bs[2][256 * 32];   // 16 KB each -> 48 KB total
    int tid  = threadIdx.x;
    int row0 = blockIdx.x * 128;
    int w = tid >> 6, lane = tid & 63;
    int wr = w >> 2, wc = w & 3;
    int r16 = lane & 15, kg = lane >> 4, kg8 = kg * 8;

    // staging geometry (16B granules): A granule gi=tid -> row=gi>>2, g=gi&3
    int rA = tid >> 2,         gA = tid & 3;
    int cB0 = tid >> 2,        gB0 = tid & 3;          // B cols 0..127
    int cB1 = (512 + tid) >> 2, gB1 = tid & 3;         // B cols 128..255

    f32x4 acc[4][4];
#pragma unroll
    for (int mi = 0; mi < 4; ++mi)
#pragma unroll
        for (int ni = 0; ni < 4; ++ni)
            acc[mi][ni] = (f32x4){0.f, 0.f, 0.f, 0.f};

    auto stage = [&](int s, int buf) {
        int k0 = s * 32;
        int seg = s >> 3;
        const ushort* Abase = (seg == 0) ? Ain : (seg == 1) ? Aout : X16p;
        int ka = k0 & 255;
        gload16(Abase + (size_t)(row0 + rA) * 256 + ka + gA * 8,
                (char*)&As[buf][0] + (size_t)(w * 64) * 16);
        gload16(wT + (size_t)cB0 * 768 + k0 + gB0 * 8,
                (char*)&Bs[buf][0] + (size_t)(w * 64) * 16);
        gload16(wT + (size_t)cB1 * 768 + k0 + gB1 * 8,
                (char*)&Bs[buf][0] + (size_t)(512 + w * 64) * 16);
    };

    stage(0, 0);
    __syncthreads();
    for (int kt = 0; kt < 24; ++kt) {
        int cur = kt & 1;
        if (kt + 1 < 24) stage(kt + 1, cur ^ 1);
        bf16x8 af[4], bfr[4];
#pragma unroll
        for (int i = 0; i < 4; ++i) {
            af[i]  = *(const bf16x8*)&As[cur][(wr * 64 + i * 16 + r16) * 32 + kg8];
            bfr[i] = *(const bf16x8*)&Bs[cur][(wc * 64 + i * 16 + r16) * 32 + kg8];
        }
#pragma unroll
        for (int mi = 0; mi < 4; ++mi)
#pragma unroll
            for (int ni = 0; ni < 4; ++ni)
                acc[mi][ni] = __builtin_amdgcn_mfma_f32_16x16x32_bf16(af[mi], bfr[ni], acc[mi][ni], 0, 0, 0);
        __syncthreads();
    }

    // ---- C16 store (bf16; aliases Ain region — block-private rows) ----
#pragma unroll
    for (int mi = 0; mi < 4; ++mi) {
        int r = row0 + wr * 64 + mi * 16 + kg * 4;
#pragma unroll
        for (int ni = 0; ni < 4; ++ni) {
            int c = wc * 64 + ni * 16 + r16;
#pragma unroll
            for (int j = 0; j < 4; ++j) {
                int rr = r + j;
                if (rr < N_ENT) C16[(size_t)rr * 256 + c] = f2b(acc[mi][ni][j]);
            }
        }
    }

    // ---- BN raw partial sums (pad rows zeroed -> contribute 0) ----
#pragma unroll
    for (int ni = 0; ni < 4; ++ni) {
        float s = 0.f, ss = 0.f;
#pragma unroll
        for (int mi = 0; mi < 4; ++mi)
#pragma unroll
            for (int j = 0; j < 4; ++j) {
                float v = acc[mi][ni][j];
                s += v; ss += v * v;
            }
        s += __shfl_xor(s, 16); ss += __shfl_xor(ss, 16);
        s += __shfl_xor(s, 32); ss += __shfl_xor(ss, 32);
        if (kg == 0) {
            int c = wc * 64 + ni * 16 + r16;
            atomicAdd(&colsum[c], s);
            atomicAdd(&colsumsq[c], ss);
        }
    }
}

// ============ fallback GEMM (reg-staged, f32-x conversion inline) ============
__global__ __launch_bounds__(256) void fused_gemm_fb_kernel(
        const ushort* __restrict__ Ain, const ushort* __restrict__ Aout,
        const float* __restrict__ xf, const float* __restrict__ lrel,
        const ushort* __restrict__ wT, float* __restrict__ C) {
    __shared__ ushort As[2][128 * 40];
    __shared__ ushort Bs[2][128 * 40];
    int tid  = threadIdx.x;
    int row0 = blockIdx.x * 128;
    int col0 = blockIdx.y * 128;
    int srow = tid >> 1, hb = tid & 1;
    int w    = tid >> 6, lane = tid & 63;
    int wr   = w >> 1,  wc = w & 1;
    int r16  = lane & 15, kg = lane >> 4;

    f32x4 acc[4][4];
#pragma unroll
    for (int mi = 0; mi < 4; ++mi)
#pragma unroll
        for (int ni = 0; ni < 4; ++ni)
            acc[mi][ni] = (f32x4){0.f, 0.f, 0.f, 0.f};

    auto stage = [&](int kt, int buf) {
        int k0 = kt * 32;
        int seg = k0 >> 8;
        int kl  = (k0 & 255) + hb * 16;
        ushort* Ad = &As[buf][srow * 40 + hb * 16];
        if (seg < 2) {
            const ushort* src = (seg ? Aout : Ain) + (size_t)(row0 + srow) * 256 + kl;
            *(us8*)Ad       = *(const us8*)src;
            *(us8*)(Ad + 8) = *(const us8*)(src + 8);
        } else {
            int gr = row0 + srow;
            us8 pa, pb;
            if (gr < N_ENT) {
                const float* src = xf + (size_t)gr * 256 + kl;
                const float* ls  = lrel + kl;
#pragma unroll
                for (int j = 0; j < 8; ++j) {
                    pa[j] = (short)f2b(src[j] * ls[j]);
                    pb[j] = (short)f2b(src[8 + j] * ls[8 + j]);
                }
            } else {
#pragma unroll
                for (int j = 0; j < 8; ++j) { pa[j] = 0; pb[j] = 0; }
            }
            *(us8*)Ad       = pa;
            *(us8*)(Ad + 8) = pb;
        }
        ushort* Bd = &Bs[buf][srow * 40 + hb * 16];
        const ushort* bsrc = wT + (size_t)(col0 + srow) * 768 + k0 + hb * 16;
        *(us8*)Bd       = *(const us8*)bsrc;
        *(us8*)(Bd + 8) = *(const us8*)(bsrc + 8);
    };

    stage(0, 0);
    __syncthreads();
    for (int kt = 0; kt < 24; ++kt) {
        int cur = kt & 1;
        if (kt + 1 < 24) stage(kt + 1, cur ^ 1);
        const ushort* Ab = &As[cur][(wr * 64 + r16) * 40 + kg * 8];
        const ushort* Bb = &Bs[cur][(wc * 64 + r16) * 40 + kg * 8];
        bf16x8 af[4], bfr[4];
#pragma unroll
        for (int i = 0; i < 4; ++i) {
            af[i]  = *(const bf16x8*)(Ab + i * 640);
            bfr[i] = *(const bf16x8*)(Bb + i * 640);
        }
#pragma unroll
        for (int mi = 0; mi < 4; ++mi)
#pragma unroll
            for (int ni = 0; ni < 4; ++ni)
                acc[mi][ni] = __builtin_amdgcn_mfma_f32_16x16x32_bf16(af[mi], bfr[ni], acc[mi][ni], 0, 0, 0);
        __syncthreads();
    }

#pragma unroll
    for (int mi = 0; mi < 4; ++mi) {
        int r = row0 + wr * 64 + mi * 16 + kg * 4;
#pragma unroll
        for (int ni = 0; ni < 4; ++ni) {
            int c = col0 + wc * 64 + ni * 16 + r16;
#pragma unroll
            for (int j = 0; j < 4; ++j) {
                int rr = r + j;
                if (rr < N_ENT) C[(size_t)rr * 256 + c] = acc[mi][ni][j];
            }
        }
    }
}

// ---------------- BatchNorm ----------------
__global__ __launch_bounds__(256) void bn_stats_kernel(
        const float* __restrict__ out, const float* __restrict__ bias,
        float* __restrict__ colsum, float* __restrict__ colsumsq) {
    int c  = threadIdx.x;
    int r0 = blockIdx.x * 64;
    float b = bias[c];
    float s = 0.f, sq = 0.f;
    int rend = min(r0 + 64, N_ENT);
    for (int r = r0; r < rend; ++r) {
        float v = out[(size_t)r * 256 + c] * (1.f / 3.f) + b;
        s += v; sq += v * v;
    }
    atomicAdd(&colsum[c], s);
    atomicAdd(&colsumsq[c], sq);
}

template<bool RAW>
__global__ void bn_finalize_kernel(const float* __restrict__ colsum, const float* __restrict__ colsumsq,
                                   const float* __restrict__ bias, const float* __restrict__ gamma,
                                   const float* __restrict__ beta,
                                   float* __restrict__ colA, float* __restrict__ colB) {
    int c = threadIdx.x;
    float invN = 1.f / N_ENT;
    float mean, var;
    if (RAW) {
        float Er  = colsum[c] * invN;
        float Er2 = colsumsq[c] * invN;
        float b = bias[c];
        mean = Er * (1.f / 3.f) + b;
        var  = Er2 * (1.f / 9.f) + 2.f * b * Er * (1.f / 3.f) + b * b - mean * mean;
    } else {
        mean = colsum[c] * invN;
        var  = colsumsq[c] * invN - mean * mean;
    }
    float sc = rsqrtf(var + BN_EPS) * gamma[c];
    colA[c] = sc * (1.f / 3.f);
    colB[c] = (bias[c] - mean) * sc + beta[c];
}

// read bf16 C16, write f32 normalized out
__global__ __launch_bounds__(256) void bn_apply16_kernel(
        const ushort* __restrict__ C16, const float* __restrict__ colA,
        const float* __restrict__ colB, float* __restrict__ out) {
    size_t i8 = ((size_t)blockIdx.x * 256 + threadIdx.x) * 8;
    us8 v = *(const us8*)(C16 + i8);
    int c = (int)(i8 & 255);
    float4 o0, o1;
    o0.x = b2f((ushort)v[0]) * colA[c + 0] + colB[c + 0];
    o0.y = b2f((ushort)v[1]) * colA[c + 1] + colB[c + 1];
    o0.z = b2f((ushort)v[2]) * colA[c + 2] + colB[c + 2];
    o0.w = b2f((ushort)v[3]) * colA[c + 3] + colB[c + 3];
    o1.x = b2f((ushort)v[4]) * colA[c + 4] + colB[c + 4];
    o1.y = b2f((ushort)v[5]) * colA[c + 5] + colB[c + 5];
    o1.z = b2f((ushort)v[6]) * colA[c + 6] + colB[c + 6];
    o1.w = b2f((ushort)v[7]) * colA[c + 7] + colB[c + 7];
    *(float4*)(out + i8)     = o0;
    *(float4*)(out + i8 + 4) = o1;
}

__global__ __launch_bounds__(256) void bn_apply_kernel(
        float* __restrict__ out, const float* __restrict__ colA, const float* __restrict__ colB) {
    size_t i4 = (size_t)blockIdx.x * 256 + threadIdx.x;
    float4 v = ((const float4*)out)[i4];
    int c4 = (int)(i4 & 63) * 4;
    v.x = v.x * colA[c4 + 0] + colB[c4 + 0];
    v.y = v.y * colA[c4 + 1] + colB[c4 + 1];
    v.z = v.z * colA[c4 + 2] + colB[c4 + 2];
    v.w = v.w * colA[c4 + 3] + colB[c4 + 3];
    ((float4*)out)[i4] = v;
}

__global__ __launch_bounds__(256) void relgemm_kernel(
        const float* __restrict__ rel, const float* __restrict__ w, float* __restrict__ out) {
    int r = blockIdx.x;
    int c = threadIdx.x;
    float acc = 0.f;
    for (int k = 0; k < 256; ++k)
        acc = fmaf(rel[r * 256 + k], w[k * 256 + c], acc);
    out[r * 256 + c] = acc;
}

extern "C" void kernel_launch(void* const* d_in, const int* in_sizes, int n_in,
                              void* d_out, int out_size, void* d_ws, size_t ws_size,
                              hipStream_t stream) {
    const float* x        = (const float*)d_in[0];
    const int*   ei       = (const int*)d_in[1];
    const int*   et       = (const int*)d_in[2];
    const float* rel      = (const float*)d_in[3];
    const float* w_loop   = (const float*)d_in[4];
    const float* w_in     = (const float*)d_in[5];
    const float* w_out    = (const float*)d_in[6];
    const float* w_rel    = (const float*)d_in[7];
    const float* loop_rel = (const float*)d_in[8];
    const float* bias     = (const float*)d_in[9];
    const float* gamma    = (const float*)d_in[10];
    const float* beta     = (const float*)d_in[11];

    float* out     = (float*)d_out;
    float* rel_out = out + (size_t)N_ENT * D;
    const int* colidx = ei + NE2;

    // ---- workspace layout (identical footprint to round 8 — proven to fit) ----
    char* ws = (char*)d_ws;
    size_t off = 0;
    ushort* agg_in16  = (ushort*)(ws + off); off += (size_t)MPAD * D * 2;
    ushort* agg_out16 = (ushort*)(ws + off); off += (size_t)MPAD * D * 2;
    int* rp_in   = (int*)(ws + off); off += 400416;
    int* rp_out  = (int*)(ws + off); off += 400416;
    float* dv_in  = (float*)(ws + off); off += 400416;
    float* dv_out = (float*)(ws + off); off += 400416;
    uint2* el2_in  = (uint2*)(ws + off); off += (size_t)EHALF * 8;
    uint2* el2_out = (uint2*)(ws + off); off += (size_t)EHALF * 8;
    ushort* wT  = (ushort*)(ws + off); off += 768 * 256 * 2;
    float* stats = (float*)(ws + off); off += 8192;
    ushort* x16   = (ushort*)(ws + off); off += (size_t)MPAD * D * 2;
    ushort* rel16 = (ushort*)(ws + off); off += (size_t)NREL * D * 2;
    size_t needed_full = off;

    float* colsum = stats, *colsumsq = stats + 256;
    float* colA = stats + 512, *colB = stats + 768;
    int* bsum = (int*)(stats + 1024);
    int* cnt_in  = (int*)agg_in16;            // dead before agg written
    int* cnt_out = cnt_in + 100004;
    ushort* C16 = agg_in16;                   // epilogue alias (block-private rows)

    if (ws_size >= needed_full) {
        // ======== full path ========
        hipMemsetAsync(cnt_in, 0, 2 * 100004 * 4, stream);

        histprep_kernel<<<PB_END, 256, 0, stream>>>(ei, cnt_in, cnt_out,
                                                    x, rel, w_in, w_out, w_loop, loop_rel, w_rel,
                                                    x16, rel16, wT, rel_out, agg_in16, agg_out16);
        scan1_kernel<<<dim3(98, 2), 256, 0, stream>>>(cnt_in, cnt_out, rp_in, rp_out, dv_in, dv_out, bsum);
        scan2_kernel<<<1, 256, 0, stream>>>(bsum, stats);
        scan3_kernel<<<dim3(98, 2), 256, 0, stream>>>(rp_in, rp_out, cnt_in, cnt_out, bsum);
        scatterp2_kernel<<<(NE2 + 255) / 256, 256, 0, stream>>>(ei, et, dv_in, dv_out,
                                                                cnt_in, cnt_out, el2_in, el2_out);

        agg2both_kernel<<<N_ENT * 64 / 256, 256, 0, stream>>>(
            rp_in, el2_in, agg_in16, rp_out, el2_out, agg_out16, x16, rel16);

        gemm5_kernel<<<MPAD / 128, 512, 0, stream>>>(
            agg_in16, agg_out16, x16, wT, C16, colsum, colsumsq);

        bn_finalize_kernel<true><<<1, 256, 0, stream>>>(colsum, colsumsq, bias, gamma, beta, colA, colB);
        bn_apply16_kernel<<<N_ENT * 64 / 512, 256, 0, stream>>>(C16, colA, colB, out);
    } else {
        // ======== mid fallback: f32 gathers, separate bn_stats ========
        int* el_in  = (int*)el2_in;
        int* el_out = el_in + EHALF;
        hipMemsetAsync(cnt_in, 0, 2 * 100004 * 4, stream);
        hist_kernel<<<(NE2 + 255) / 256, 256, 0, stream>>>(ei, cnt_in, cnt_out);
        scan1_kernel<<<dim3(98, 2), 256, 0, stream>>>(cnt_in, cnt_out, rp_in, rp_out, dv_in, dv_out, bsum);
        scan2_kernel<<<1, 256, 0, stream>>>(bsum, stats);
        scan3_kernel<<<dim3(98, 2), 256, 0, stream>>>(rp_in, rp_out, cnt_in, cnt_out, bsum);
        scatter_kernel<<<(NE2 + 255) / 256, 256, 0, stream>>>(ei, cnt_in, cnt_out, el_in, el_out);
        wconv_kernel<<<256, 256, 0, stream>>>(w_in, w_out, w_loop, wT);

        agg_csr16_kernel<<<(N_ENT * 64 + 255) / 256, 256, 0, stream>>>(
            rp_in, el_in, colidx, et, dv_in, x, rel, agg_in16);
        agg_csr16_kernel<<<(N_ENT * 64 + 255) / 256, 256, 0, stream>>>(
            rp_out, el_out, colidx, et, dv_out, x, rel, agg_out16);

        fused_gemm_fb_kernel<<<dim3(MPAD / 128, 2), 256, 0, stream>>>(
            agg_in16, agg_out16, x, loop_rel, wT, out);

        bn_stats_kernel<<<(N_ENT + 63) / 64, 256, 0, stream>>>(out, bias, colsum, colsumsq);
        bn_finalize_kernel<false><<<1, 256, 0, stream>>>(colsum, colsumsq, bias, gamma, beta, colA, colB);
        bn_apply_kernel<<<(N_ENT * 64) / 256, 256, 0, stream>>>(out, colA, colB);
        relgemm_kernel<<<NREL, 256, 0, stream>>>(rel, w_rel, rel_out);
    }
}